// Round 1
// baseline (227.427 us; speedup 1.0000x reference)
//
#include <hip/hip_runtime.h>
#include <math.h>

#define H      2048
#define NEXP   64
#define TOKENS 16384
#define BATCH  4
#define SEQ    4096
#define HC     64        // H chunk staged per iteration
#define TPW    8         // tokens per wave
#define NWAVES 4
#define TPB    (TPW * NWAVES)   // 32 tokens per block
#define WPAD   (HC + 4)         // padded W row stride in LDS (floats)

__global__ __launch_bounds__(256, 2)
void router_main(const float* __restrict__ x, const float* __restrict__ W,
                 float* __restrict__ out, float* __restrict__ ws)
{
    __shared__ float lds_x[TPB][HC];     // 8 KiB
    __shared__ float lds_w[NEXP][WPAD];  // 17 KiB, +4 float pad vs 256B stride
    __shared__ float lds_psum[NEXP];
    __shared__ float lds_cnt[NEXP];

    const int tid  = threadIdx.x;
    const int lane = tid & 63;
    const int wv   = tid >> 6;
    const int tb0  = blockIdx.x * TPB;

    if (tid < NEXP) { lds_psum[tid] = 0.f; lds_cnt[tid] = 0.f; }

    float acc[TPW];
    #pragma unroll
    for (int i = 0; i < TPW; ++i) acc[i] = 0.f;

    for (int h0 = 0; h0 < H; h0 += HC) {
        __syncthreads();   // also covers the psum/cnt init on iter 0
        // stage x tile: 32 rows x 64 cols = 512 float4, 2 per thread
        {
            int g = tid;
            #pragma unroll
            for (int r = 0; r < 2; ++r, g += 256) {
                const int row = g >> 4, c4 = g & 15;
                const float4 v = *reinterpret_cast<const float4*>(
                    &x[(size_t)(tb0 + row) * H + h0 + c4 * 4]);
                *reinterpret_cast<float4*>(&lds_x[row][c4 * 4]) = v;
            }
            // stage W chunk: 64 rows x 64 cols = 1024 float4, 4 per thread
            g = tid;
            #pragma unroll
            for (int r = 0; r < 4; ++r, g += 256) {
                const int row = g >> 4, c4 = g & 15;
                const float4 v = *reinterpret_cast<const float4*>(
                    &W[(size_t)row * H + h0 + c4 * 4]);
                *reinterpret_cast<float4*>(&lds_w[row][c4 * 4]) = v;
            }
        }
        __syncthreads();
        #pragma unroll
        for (int j4 = 0; j4 < HC / 4; ++j4) {
            const float4 wv4 = *reinterpret_cast<const float4*>(&lds_w[lane][j4 * 4]);
            #pragma unroll
            for (int t = 0; t < TPW; ++t) {
                const float4 xv4 = *reinterpret_cast<const float4*>(
                    &lds_x[wv * TPW + t][j4 * 4]);   // broadcast read
                acc[t] = fmaf(xv4.x, wv4.x, acc[t]);
                acc[t] = fmaf(xv4.y, wv4.y, acc[t]);
                acc[t] = fmaf(xv4.z, wv4.z, acc[t]);
                acc[t] = fmaf(xv4.w, wv4.w, acc[t]);
            }
        }
    }

    // acc[t] = logits[token tb0+wv*8+t][expert=lane]
    float psum = 0.f;
    #pragma unroll
    for (int t = 0; t < TPW; ++t) {
        const float l = acc[t];
        // top-1 (tie -> lower index, matching lax.top_k stability)
        float v1 = l; int i1 = lane;
        #pragma unroll
        for (int off = 32; off > 0; off >>= 1) {
            const float ov = __shfl_xor(v1, off, 64);
            const int   oi = __shfl_xor(i1, off, 64);
            if (ov > v1 || (ov == v1 && oi < i1)) { v1 = ov; i1 = oi; }
        }
        // top-2: exclude i1
        float v2 = (lane == i1) ? -INFINITY : l; int i2 = lane;
        #pragma unroll
        for (int off = 32; off > 0; off >>= 1) {
            const float ov = __shfl_xor(v2, off, 64);
            const int   oi = __shfl_xor(i2, off, 64);
            if (ov > v2 || (ov == v2 && oi < i2)) { v2 = ov; i2 = oi; }
        }
        // full softmax denominator
        const float ex = expf(l - v1);
        float den = ex;
        #pragma unroll
        for (int off = 32; off > 0; off >>= 1) den += __shfl_xor(den, off, 64);
        psum += ex / den;   // this lane's expert score for this token

        if (lane == 0) {
            const int gt = tb0 + wv * TPW + t;
            const float s1 = 1.0f / den;            // exp(v1-v1)/den
            const float s2 = expf(v2 - v1) / den;
            const float inv = 1.0f / (s1 + s2 + 1e-20f);
            out[2 * gt]     = (float)i1;
            out[2 * gt + 1] = (float)i2;
            out[2 * TOKENS + 2 * gt]     = s1 * inv;
            out[2 * TOKENS + 2 * gt + 1] = s2 * inv;
            atomicAdd(&lds_cnt[i1], 1.f);
            atomicAdd(&lds_cnt[i2], 1.f);
        }
    }
    atomicAdd(&lds_psum[lane], psum);
    __syncthreads();
    if (tid < NEXP) {
        const int b = tb0 >> 12;   // /4096 tokens per batch; block never straddles
        atomicAdd(&ws[b * NEXP + tid], lds_psum[tid]);
        atomicAdd(&ws[BATCH * NEXP + b * NEXP + tid], lds_cnt[tid]);
    }
}

__global__ void router_aux(const float* __restrict__ ws, float* __restrict__ out)
{
    const int tid = threadIdx.x;    // 256 = B*E entries
    const float psum = ws[tid];
    const float cnt  = ws[BATCH * NEXP + tid];
    // ce = cnt * E/(S*k);  meanprob = psum/S
    float val = cnt * (64.0f / (4096.0f * 2.0f)) * (psum / 4096.0f);
    #pragma unroll
    for (int off = 32; off > 0; off >>= 1) val += __shfl_xor(val, off, 64);
    __shared__ float red[4];
    if ((tid & 63) == 0) red[tid >> 6] = val;
    __syncthreads();
    if (tid == 0)
        out[4 * TOKENS] = (red[0] + red[1] + red[2] + red[3]) * (0.001f / 4.0f);
}

extern "C" void kernel_launch(void* const* d_in, const int* in_sizes, int n_in,
                              void* d_out, int out_size, void* d_ws, size_t ws_size,
                              hipStream_t stream)
{
    const float* x = (const float*)d_in[0];
    const float* W = (const float*)d_in[1];
    float* out = (float*)d_out;
    float* ws  = (float*)d_ws;

    hipMemsetAsync(d_ws, 0, 2 * BATCH * NEXP * sizeof(float), stream);
    hipLaunchKernelGGL(router_main, dim3(TOKENS / TPB), dim3(256), 0, stream,
                       x, W, out, ws);
    hipLaunchKernelGGL(router_aux, dim3(1), dim3(256), 0, stream, ws, out);
}

// Round 2
// 103.697 us; speedup vs baseline: 2.1932x; 2.1932x over previous
//
#include <hip/hip_runtime.h>
#include <math.h>

#define H       2048
#define E       64
#define TOKENS  16384
#define SEQ     4096
#define BATCH   4
#define CH      128              // h staged per chunk
#define NCH     (H / CH)         // 16 chunks
#define TPB_TOK 64               // tokens per block (= lanes)

// ws layout in floats
#define WT_OFF   0
#define WT_SZ    (H * E)                 // 131072 floats = 512 KB
#define PSUM_OFF WT_SZ                   // BATCH*E floats
#define CNT_OFF  (WT_SZ + BATCH * E)     // BATCH*E floats

// ---------------- W transpose: W[e][h] -> Wt[h][e] ----------------
__global__ __launch_bounds__(256)
void transpose_w(const float* __restrict__ W, float* __restrict__ Wt)
{
    __shared__ float t[64][65];
    const int h0 = blockIdx.x * 64;
    const int tid = threadIdx.x;
    const int c  = tid & 63;
    const int r4 = tid >> 6;
    #pragma unroll
    for (int i = 0; i < 16; ++i) {
        const int e = i * 4 + r4;
        t[e][c] = W[(size_t)e * H + h0 + c];
    }
    __syncthreads();
    #pragma unroll
    for (int i = 0; i < 16; ++i) {
        const int hl = i * 4 + r4;
        Wt[(size_t)(h0 + hl) * E + c] = t[c][hl];
    }
}

// ---------------- main router kernel ----------------
// block = 1024 threads = 16 waves; lane = token; wave = h-slice owner.
__global__ __launch_bounds__(1024, 4)
void router_main(const float* __restrict__ x, const float* __restrict__ Wt,
                 float* __restrict__ out, float* __restrict__ psum_g,
                 float* __restrict__ cnt_g)
{
    __shared__ float lds[16384];   // 64 KB: 2x 32KB x-staging, reused as 4x 16KB reduce slots

    const int tid = threadIdx.x;
    const int l   = tid & 63;                                   // lane = local token
    const int w   = __builtin_amdgcn_readfirstlane(tid >> 6);   // wave id (uniform)
    const int t0  = blockIdx.x * TPB_TOK;

    float acc[E];
    #pragma unroll
    for (int e = 0; e < E; ++e) acc[e] = 0.f;

    // ---- staging: global (linear, coalesced) -> regs -> LDS (XOR-swizzled rows)
    auto stage_load = [&](int c, float4* v) {
        #pragma unroll
        for (int i = 0; i < 2; ++i) {
            const int g  = w * 2 + i;
            const int tt = 2 * g + (l >> 5);      // token row 0..63
            const int u  = l & 31;                // 16B unit within 512B row
            v[i] = *(const float4*)(x + (size_t)(t0 + tt) * H + c * CH + u * 4);
        }
    };
    auto stage_write = [&](int buf, const float4* v) {
        #pragma unroll
        for (int i = 0; i < 2; ++i) {
            const int g  = w * 2 + i;
            const int tt = 2 * g + (l >> 5);
            const int us = (l & 31) ^ (tt & 31);  // swizzled slot
            *(float4*)&lds[buf * 8192 + tt * 128 + us * 4] = v[i];
        }
    };

    // ---- compute one chunk: this wave's 8 h-values x 64 experts
    auto compute = [&](int buf, int c) {
        const int bf = buf * 8192 + l * 128;
        const int u0 = (2 * w)     ^ (l & 31);
        const int u1 = (2 * w + 1) ^ (l & 31);
        const float4 xa = *(const float4*)&lds[bf + u0 * 4];
        const float4 xb = *(const float4*)&lds[bf + u1 * 4];
        const float xs_[8] = {xa.x, xa.y, xa.z, xa.w, xb.x, xb.y, xb.z, xb.w};
        const float* wr = Wt + (size_t)(c * CH + w * 8) * E;   // uniform -> s_load
        #pragma unroll
        for (int j = 0; j < 8; ++j) {
            const float xs = xs_[j];
            #pragma unroll
            for (int u = 0; u < 16; ++u) {
                const float4 w4 = *(const float4*)(wr + j * E + u * 4);
                acc[4*u+0] = fmaf(xs, w4.x, acc[4*u+0]);
                acc[4*u+1] = fmaf(xs, w4.y, acc[4*u+1]);
                acc[4*u+2] = fmaf(xs, w4.z, acc[4*u+2]);
                acc[4*u+3] = fmaf(xs, w4.w, acc[4*u+3]);
            }
        }
    };

    // ---- main loop, double-buffered
    {
        float4 v[2];
        stage_load(0, v);
        stage_write(0, v);
        __syncthreads();
        for (int c = 0; c < NCH; ++c) {
            float4 vn[2];
            if (c + 1 < NCH) stage_load(c + 1, vn);   // hide HBM latency under FMAs
            compute(c & 1, c);
            __syncthreads();                          // everyone done reading buf[(c+1)&1]
            if (c + 1 < NCH) stage_write((c + 1) & 1, vn);
            __syncthreads();
        }
    }

    // ---- cross-wave reduction of acc over the 16 h-slices (4x 16KB slots)
    auto write_acc = [&](int slot) {
        float* base = &lds[slot * 4096 + l * 64];
        #pragma unroll
        for (int u = 0; u < 16; ++u) {
            const int up = u ^ (l & 15);
            *(float4*)(base + up * 4) = make_float4(acc[4*u], acc[4*u+1], acc[4*u+2], acc[4*u+3]);
        }
    };
    auto add_from = [&](int slot) {
        const float* base = &lds[slot * 4096 + l * 64];
        #pragma unroll
        for (int u = 0; u < 16; ++u) {
            const int up = u ^ (l & 15);
            const float4 vv = *(const float4*)(base + up * 4);
            acc[4*u+0] += vv.x; acc[4*u+1] += vv.y; acc[4*u+2] += vv.z; acc[4*u+3] += vv.w;
        }
    };

    if (w >= 8 && w < 12) write_acc(w - 8);
    __syncthreads();
    if (w < 4)            add_from(w);          // w0-3 += w8-11
    __syncthreads();
    if (w >= 12)          write_acc(w - 12);
    __syncthreads();
    if (w >= 4 && w < 8)  add_from(w - 4);      // w4-7 += w12-15
    __syncthreads();
    if (w >= 4 && w < 8)  write_acc(w - 4);
    __syncthreads();
    if (w < 4)            add_from(w);          // w0-3 += w4-7
    __syncthreads();
    if (w >= 2 && w < 4)  write_acc(w - 2);
    __syncthreads();
    if (w < 2)            add_from(w);          // w0-1 += w2-3
    __syncthreads();
    if (w == 1)           write_acc(0);
    __syncthreads();
    if (w == 0)           add_from(0);          // wave 0: full logits per lane
    __syncthreads();

    // ---- per-lane serial top-2 + softmax (wave 0 only; logits live in one lane)
    const int bidx = blockIdx.x >> 6;   // 64 blocks per batch
    int i1 = 0, i2 = 0;
    if (w == 0) {
        float v1 = acc[0];
        #pragma unroll
        for (int e = 1; e < E; ++e) { if (acc[e] > v1) { v1 = acc[e]; i1 = e; } }
        float v2 = -INFINITY;
        #pragma unroll
        for (int e = 0; e < E; ++e) {
            if (e != i1 && acc[e] > v2) { v2 = acc[e]; i2 = e; }
        }
        float den = 0.f;
        #pragma unroll
        for (int e = 0; e < E; ++e) den += __expf(acc[e] - v1);
        const float inv_den = 1.f / den;
        const float s1 = inv_den;                       // exp(v1-v1)/den
        const float s2 = __expf(v2 - v1) * inv_den;
        const float rs = 1.f / (s1 + s2 + 1e-20f);
        const int gt = t0 + l;
        *(float2*)&out[2 * gt]              = make_float2((float)i1, (float)i2);
        *(float2*)&out[2 * TOKENS + 2 * gt] = make_float2(s1 * rs, s2 * rs);
        // scores -> LDS (rotated columns: conflict-free write & column read)
        #pragma unroll
        for (int e = 0; e < E; ++e)
            lds[l * 64 + ((e + l) & 63)] = __expf(acc[e] - v1) * inv_den;
    }
    __syncthreads();
    if (w == 0) {
        float cs = 0.f;                 // sum of scores for expert l over 64 tokens
        #pragma unroll
        for (int r = 0; r < 64; ++r) cs += lds[r * 64 + ((l + r) & 63)];
        atomicAdd(&psum_g[bidx * E + l], cs);
        lds[4096 + l] = 0.f;            // zero histogram
    }
    __syncthreads();
    if (w == 0) {
        atomicAdd(&lds[4096 + i1], 1.f);
        atomicAdd(&lds[4096 + i2], 1.f);
    }
    __syncthreads();
    if (w == 0) {
        atomicAdd(&cnt_g[bidx * E + l], lds[4096 + l]);
    }
}

// ---------------- aux loss finalize ----------------
__global__ void router_aux(const float* __restrict__ ws, float* __restrict__ out)
{
    const int tid = threadIdx.x;    // 256 = BATCH*E
    const float psum = ws[PSUM_OFF + tid];
    const float cnt  = ws[CNT_OFF + tid];
    // ce = cnt * E/(S*k); meanprob = psum/S
    float val = cnt * (64.0f / (4096.0f * 2.0f)) * (psum / 4096.0f);
    #pragma unroll
    for (int off = 32; off > 0; off >>= 1) val += __shfl_xor(val, off, 64);
    __shared__ float red[4];
    if ((tid & 63) == 0) red[tid >> 6] = val;
    __syncthreads();
    if (tid == 0)
        out[4 * TOKENS] = (red[0] + red[1] + red[2] + red[3]) * (0.001f / 4.0f);
}

extern "C" void kernel_launch(void* const* d_in, const int* in_sizes, int n_in,
                              void* d_out, int out_size, void* d_ws, size_t ws_size,
                              hipStream_t stream)
{
    (void)in_sizes; (void)n_in; (void)out_size; (void)ws_size;
    const float* x = (const float*)d_in[0];
    const float* W = (const float*)d_in[1];
    float* out = (float*)d_out;
    float* ws  = (float*)d_ws;

    hipMemsetAsync(ws + PSUM_OFF, 0, 2 * BATCH * E * sizeof(float), stream);
    hipLaunchKernelGGL(transpose_w, dim3(H / 64), dim3(256), 0, stream, W, ws + WT_OFF);
    hipLaunchKernelGGL(router_main, dim3(TOKENS / TPB_TOK), dim3(1024), 0, stream,
                       x, ws + WT_OFF, out, ws + PSUM_OFF, ws + CNT_OFF);
    hipLaunchKernelGGL(router_aux, dim3(1), dim3(256), 0, stream, ws, out);
}

// Round 3
// 49.962 us; speedup vs baseline: 4.5520x; 2.0755x over previous
//
#include <hip/hip_runtime.h>
#include <math.h>

#define H       2048
#define E       64
#define TOKENS  16384
#define BATCH   4

typedef _Float16 f16x8 __attribute__((ext_vector_type(8)));
typedef float    f32x4 __attribute__((ext_vector_type(4)));

// ws float offsets
#define WHI_OFF  0          // 131072 f16 = 65536 floats
#define WLO_OFF  65536
#define PSUM_OFF 131072     // BATCH*E
#define CNT_OFF  131328     // BATCH*E

// ---- W fp32 -> tiled f16 hi/lo in MFMA B-fragment order ----
// slot s = (kk*4 + et)*64 + lane; element j = Whl[e=et*16+(l&15)][kk*32+(l>>4)*8+j]
__global__ __launch_bounds__(256)
void wconv(const float* __restrict__ W, _Float16* __restrict__ whi, _Float16* __restrict__ wlo)
{
    const int s  = blockIdx.x * 256 + threadIdx.x;   // 0..16383
    const int kk = s >> 8;
    const int et = (s >> 6) & 3;
    const int l  = s & 63;
    const int e  = et * 16 + (l & 15);
    const int kb = kk * 32 + ((l >> 4) << 3);
    const float4 a = *(const float4*)(W + (size_t)e * H + kb);
    const float4 b = *(const float4*)(W + (size_t)e * H + kb + 4);
    const float xv[8] = {a.x, a.y, a.z, a.w, b.x, b.y, b.z, b.w};
    f16x8 hi, lo;
    #pragma unroll
    for (int j = 0; j < 8; ++j) {
        const _Float16 h = (_Float16)xv[j];
        hi[j] = h;
        lo[j] = (_Float16)(xv[j] - (float)h);
    }
    *(f16x8*)(whi + (size_t)s * 8) = hi;
    *(f16x8*)(wlo + (size_t)s * 8) = lo;
}

// ---- main: 256 blocks x 1024 thr; wave = (tg 0..3 token-tile, ks 0..3 K-slice) ----
__global__ __launch_bounds__(1024, 4)
void router_main(const float* __restrict__ x,
                 const _Float16* __restrict__ whi,
                 const _Float16* __restrict__ wlo,
                 float* __restrict__ out,
                 float* __restrict__ psum_g, float* __restrict__ cnt_g)
{
    __shared__ float lds[16384];   // 64 KB: [4 tg][4 ks][16 t][64 e] partials, then reused

    const int tid = threadIdx.x;
    const int l   = tid & 63;
    const int w   = tid >> 6;
    const int tg  = w & 3;
    const int ks  = w >> 2;

    const int    trow  = blockIdx.x * 64 + tg * 16 + (l & 15);     // A row = lane&15
    const float* xbase = x + (size_t)trow * H + ks * 512 + ((l >> 4) << 3);
    const f16x8* bh_base = (const f16x8*)whi + (size_t)(ks * 16) * 256 + l;
    const f16x8* bl_base = (const f16x8*)wlo + (size_t)(ks * 16) * 256 + l;

    f32x4 acc[4];
    #pragma unroll
    for (int et = 0; et < 4; ++et) acc[et] = (f32x4){0.f, 0.f, 0.f, 0.f};

    float4 a0 = *(const float4*)xbase;
    float4 a1 = *(const float4*)(xbase + 4);

    #pragma unroll
    for (int kk = 0; kk < 16; ++kk) {
        // prefetch next A (HBM) while this step computes
        float4 n0 = a0, n1 = a1;
        if (kk < 15) {
            n0 = *(const float4*)(xbase + (kk + 1) * 32);
            n1 = *(const float4*)(xbase + (kk + 1) * 32 + 4);
        }
        // B frags (L2-hot, coalesced)
        f16x8 bh[4], bl[4];
        #pragma unroll
        for (int et = 0; et < 4; ++et) {
            bh[et] = bh_base[kk * 256 + et * 64];
            bl[et] = bl_base[kk * 256 + et * 64];
        }
        // split A into f16 hi/lo (residual exact in fp32)
        const float xv[8] = {a0.x, a0.y, a0.z, a0.w, a1.x, a1.y, a1.z, a1.w};
        f16x8 ahi, alo;
        #pragma unroll
        for (int j = 0; j < 8; ++j) {
            const _Float16 h = (_Float16)xv[j];
            ahi[j] = h;
            alo[j] = (_Float16)(xv[j] - (float)h);
        }
        #pragma unroll
        for (int et = 0; et < 4; ++et) {
            acc[et] = __builtin_amdgcn_mfma_f32_16x16x32_f16(ahi, bh[et], acc[et], 0, 0, 0);
            acc[et] = __builtin_amdgcn_mfma_f32_16x16x32_f16(ahi, bl[et], acc[et], 0, 0, 0);
            acc[et] = __builtin_amdgcn_mfma_f32_16x16x32_f16(alo, bh[et], acc[et], 0, 0, 0);
        }
        a0 = n0; a1 = n1;
    }

    // ---- write K-slice partials: C row=(l>>4)*4+i (token-local), col=lane&15 (expert-local)
    __syncthreads();
    #pragma unroll
    for (int et = 0; et < 4; ++et)
        #pragma unroll
        for (int i = 0; i < 4; ++i) {
            const int t = ((l >> 4) << 2) + i;
            const int e = et * 16 + (l & 15);
            lds[((tg * 4 + ks) * 16 + t) * 64 + e] = acc[et][i];
        }
    __syncthreads();

    // ---- reduce over ks (1024 lanes x 4 outputs), write final [64][65]
    {
        const int t_g = tid >> 4;            // 0..63
        const int e4  = (tid & 15) * 4;
        const int tg2 = t_g >> 4, tl = t_g & 15;
        float s0 = 0.f, s1 = 0.f, s2 = 0.f, s3 = 0.f;
        #pragma unroll
        for (int k2 = 0; k2 < 4; ++k2) {
            const float4 v = *(const float4*)&lds[((tg2 * 4 + k2) * 16 + tl) * 64 + e4];
            s0 += v.x; s1 += v.y; s2 += v.z; s3 += v.w;
        }
        __syncthreads();    // all partial reads done before overwriting region
        lds[t_g * 65 + e4 + 0] = s0;
        lds[t_g * 65 + e4 + 1] = s1;
        lds[t_g * 65 + e4 + 2] = s2;
        lds[t_g * 65 + e4 + 3] = s3;
    }
    __syncthreads();

    // ---- wave-0 epilogue: lane = token (proven round-2 structure)
    const int bidx = blockIdx.x >> 6;   // 64 blocks per batch
    int i1 = 0, i2 = 0;
    if (w == 0) {
        float lg[64];
        #pragma unroll
        for (int e = 0; e < 64; ++e) lg[e] = lds[l * 65 + e];
        float v1 = lg[0];
        #pragma unroll
        for (int e = 1; e < 64; ++e) { if (lg[e] > v1) { v1 = lg[e]; i1 = e; } }
        float v2 = -INFINITY;
        #pragma unroll
        for (int e = 0; e < 64; ++e) { if (e != i1 && lg[e] > v2) { v2 = lg[e]; i2 = e; } }
        float den = 0.f;
        #pragma unroll
        for (int e = 0; e < 64; ++e) den += __expf(lg[e] - v1);
        const float inv_den = 1.f / den;
        const float s1 = inv_den;                    // exp(v1-v1)/den
        const float s2 = __expf(v2 - v1) * inv_den;
        const float rs = 1.f / (s1 + s2 + 1e-20f);
        const int gt = blockIdx.x * 64 + l;
        *(float2*)&out[2 * gt]              = make_float2((float)i1, (float)i2);
        *(float2*)&out[2 * TOKENS + 2 * gt] = make_float2(s1 * rs, s2 * rs);
        // scores, rotated columns for conflict-free column sums
        #pragma unroll
        for (int e = 0; e < 64; ++e)
            lds[8192 + l * 64 + ((e + l) & 63)] = __expf(lg[e] - v1) * inv_den;
    }
    __syncthreads();
    if (w == 0) {
        float cs = 0.f;
        #pragma unroll
        for (int r = 0; r < 64; ++r) cs += lds[8192 + r * 64 + ((l + r) & 63)];
        atomicAdd(&psum_g[bidx * E + l], cs);
        lds[12288 + l] = 0.f;
    }
    __syncthreads();
    if (w == 0) {
        atomicAdd(&lds[12288 + i1], 1.f);
        atomicAdd(&lds[12288 + i2], 1.f);
    }
    __syncthreads();
    if (w == 0) atomicAdd(&cnt_g[bidx * E + l], lds[12288 + l]);
}

// ---- aux loss finalize ----
__global__ __launch_bounds__(256)
void router_aux(const float* __restrict__ ws, float* __restrict__ out)
{
    const int tid = threadIdx.x;    // 256 = BATCH*E
    const float psum = ws[PSUM_OFF + tid];
    const float cnt  = ws[CNT_OFF + tid];
    float val = cnt * (64.0f / (4096.0f * 2.0f)) * (psum / 4096.0f);
    #pragma unroll
    for (int off = 32; off > 0; off >>= 1) val += __shfl_xor(val, off, 64);
    __shared__ float red[4];
    if ((tid & 63) == 0) red[tid >> 6] = val;
    __syncthreads();
    if (tid == 0)
        out[4 * TOKENS] = (red[0] + red[1] + red[2] + red[3]) * (0.001f / 4.0f);
}

extern "C" void kernel_launch(void* const* d_in, const int* in_sizes, int n_in,
                              void* d_out, int out_size, void* d_ws, size_t ws_size,
                              hipStream_t stream)
{
    (void)in_sizes; (void)n_in; (void)out_size; (void)ws_size;
    const float* x = (const float*)d_in[0];
    const float* W = (const float*)d_in[1];
    float* out = (float*)d_out;
    float* ws  = (float*)d_ws;

    _Float16* whi = (_Float16*)(ws + WHI_OFF);
    _Float16* wlo = (_Float16*)(ws + WLO_OFF);

    hipMemsetAsync(ws + PSUM_OFF, 0, 2 * BATCH * E * sizeof(float), stream);
    hipLaunchKernelGGL(wconv, dim3(64), dim3(256), 0, stream, W, whi, wlo);
    hipLaunchKernelGGL(router_main, dim3(TOKENS / 64), dim3(1024), 0, stream,
                       x, whi, wlo, out, ws + PSUM_OFF, ws + CNT_OFF);
    hipLaunchKernelGGL(router_aux, dim3(1), dim3(256), 0, stream, ws, out);
}